// Round 3
// baseline (716.433 us; speedup 1.0000x reference)
//
#include <hip/hip_runtime.h>
#include <hip/hip_bf16.h>
#include <math.h>
#include <cstdint>

#define S_LEN 2048
#define DKH 64

typedef __attribute__((ext_vector_type(8))) short s16x8;
typedef __attribute__((ext_vector_type(4))) short s16x4;
typedef __attribute__((ext_vector_type(4))) float f32x4;
typedef __attribute__((ext_vector_type(16))) float f32x16;

__device__ __forceinline__ unsigned short f2bf(float f) {
  unsigned int u = __float_as_uint(f);
  return (unsigned short)((u + 0x7fffu + ((u >> 16) & 1u)) >> 16);
}
__device__ __forceinline__ unsigned int pack2bf(float a, float b) {
  return (unsigned int)f2bf(a) | ((unsigned int)f2bf(b) << 16);
}

// async global->LDS, 16B per lane, wave-uniform LDS base
__device__ __forceinline__ void glds16(const unsigned short* g, unsigned short* l) {
  __builtin_amdgcn_global_load_lds(
      (const __attribute__((address_space(1))) unsigned int*)(uintptr_t)g,
      (__attribute__((address_space(3))) unsigned int*)(uintptr_t)l, 16, 0, 0);
}

// ---------------- prep: rope table ----------------
__global__ void k_rope_table(float* __restrict__ cosT, float* __restrict__ sinT) {
  int idx = blockIdx.x * 256 + threadIdx.x;  // 2048*32
  if (idx >= S_LEN * 32) return;
  int s = idx >> 5, i = idx & 31;
  float theta = powf(10000.0f, -(float)i / 32.0f);
  float ang = (float)s * theta;
  float sv, cv;
  sincosf(ang, &sv, &cv);
  cosT[idx] = cv;
  sinT[idx] = sv;
}

// ---------------- prep: weight transpose f32[1024][1024] -> bf16 WT[n][k] ----------------
__global__ __launch_bounds__(256) void k_wtrans(const float* __restrict__ W,
                                                unsigned short* __restrict__ WT) {
  __shared__ float t[32][33];
  int n0 = blockIdx.x * 32, k0 = blockIdx.y * 32;
  int tx = threadIdx.x & 31, ty = threadIdx.x >> 5;
#pragma unroll
  for (int p = 0; p < 4; ++p)
    t[ty + p * 8][tx] = W[(size_t)(k0 + ty + p * 8) * 1024 + n0 + tx];
  __syncthreads();
#pragma unroll
  for (int p = 0; p < 4; ++p)
    WT[(size_t)(n0 + ty + p * 8) * 1024 + k0 + tx] = f2bf(t[tx][ty + p * 8]);
}

// ---------------- prep: Q f32 -> bf16 ----------------
__global__ __launch_bounds__(256) void k_qconv(const float* __restrict__ Q,
                                               unsigned short* __restrict__ Qbf) {
  int idx = (blockIdx.x * 256 + threadIdx.x) * 8;
  float4 a = *(const float4*)(Q + idx);
  float4 b = *(const float4*)(Q + idx + 4);
  s16x8 o;
  o[0] = (short)f2bf(a.x); o[1] = (short)f2bf(a.y); o[2] = (short)f2bf(a.z); o[3] = (short)f2bf(a.w);
  o[4] = (short)f2bf(b.x); o[5] = (short)f2bf(b.y); o[6] = (short)f2bf(b.z); o[7] = (short)f2bf(b.w);
  *(s16x8*)(Qbf + idx) = o;
}

// ---------------- prep: v transpose  vl[bh][s][d] -> vt[bh][d][s] (bf16) ----------------
__global__ __launch_bounds__(256) void k_vtrans(const unsigned short* __restrict__ vl,
                                                unsigned short* __restrict__ vt) {
  __shared__ unsigned short t[64][65];
  int bh = blockIdx.y;
  int s0 = blockIdx.x * 64;
  int tx = threadIdx.x & 3;
  int r = threadIdx.x >> 2;
  const unsigned short* src = vl + (size_t)bh * S_LEN * DKH + (size_t)s0 * DKH;
  s16x8 a = *(const s16x8*)(src + r * 64 + tx * 16);
  s16x8 b = *(const s16x8*)(src + r * 64 + tx * 16 + 8);
#pragma unroll
  for (int j = 0; j < 8; ++j) { t[r][tx * 16 + j] = (unsigned short)a[j]; t[r][tx * 16 + 8 + j] = (unsigned short)b[j]; }
  __syncthreads();
  unsigned short* dst = vt + (size_t)bh * DKH * S_LEN + (size_t)r * S_LEN + s0;
  s16x8 o0, o1;
#pragma unroll
  for (int j = 0; j < 8; ++j) { o0[j] = (short)t[tx * 16 + j][r]; o1[j] = (short)t[tx * 16 + 8 + j][r]; }
  *(s16x8*)(dst + tx * 16) = o0;
  *(s16x8*)(dst + tx * 16 + 8) = o1;
}

// ---------------- QKV projection GEMM (m97-style) + bias + RoPE ----------------
__global__ __launch_bounds__(256) void k_qkv(
    const unsigned short* __restrict__ Qbf, const unsigned short* __restrict__ WTqkv,
    const float* __restrict__ bq, const float* __restrict__ bk, const float* __restrict__ bv,
    const float* __restrict__ cosT, const float* __restrict__ sinT,
    unsigned short* __restrict__ ql, unsigned short* __restrict__ kl,
    unsigned short* __restrict__ vl) {
  __shared__ unsigned short As[128 * 64];
  __shared__ unsigned short Bs[128 * 64];
  const int m0 = blockIdx.y * 128, n0 = blockIdx.x * 128;
  const int tid = threadIdx.x, lane = tid & 63, wave = tid >> 6;
  const int wm = (wave >> 1) * 64, wn = (wave & 1) * 64;
  const int lr = lane & 15, lg = lane >> 4;
  const int widx = n0 >> 10;  // 0=q 1=k 2=v
  const float* bias = widx == 0 ? bq : (widx == 1 ? bk : bv);
  const int lrow = lane >> 3, lcol = (lane & 7) * 8;

  f32x4 acc[4][4] = {};
  for (int k0 = 0; k0 < 1024; k0 += 64) {
    __syncthreads();
#pragma unroll
    for (int i = 0; i < 4; ++i) {
      int chunk = wave * 4 + i;
      glds16(Qbf + (size_t)(m0 + 8 * chunk + lrow) * 1024 + k0 + lcol, &As[chunk * 512]);
      glds16(WTqkv + (size_t)(n0 + 8 * chunk + lrow) * 1024 + k0 + lcol, &Bs[chunk * 512]);
    }
    __syncthreads();
#pragma unroll
    for (int ks = 0; ks < 2; ++ks) {
      s16x8 af[4], bf[4];
#pragma unroll
      for (int i = 0; i < 4; ++i) af[i] = *(const s16x8*)&As[(wm + i * 16 + lr) * 64 + ks * 32 + lg * 8];
#pragma unroll
      for (int i = 0; i < 4; ++i) bf[i] = *(const s16x8*)&Bs[(wn + i * 16 + lr) * 64 + ks * 32 + lg * 8];
#pragma unroll
      for (int mi = 0; mi < 4; ++mi)
#pragma unroll
        for (int ni = 0; ni < 4; ++ni)
          acc[mi][ni] = __builtin_amdgcn_mfma_f32_16x16x32_bf16(af[mi], bf[ni], acc[mi][ni], 0, 0, 0);
    }
  }

#pragma unroll
  for (int ni = 0; ni < 4; ++ni) {
    int n = n0 + wn + ni * 16 + lr;
    int np = n & 1023;
    float bval = bias[np];
    int h = np >> 6, d = np & 63;
    int ia = d >> 1;
#pragma unroll
    for (int mi = 0; mi < 4; ++mi) {
#pragma unroll
      for (int r = 0; r < 4; ++r) {
        int m = m0 + wm + mi * 16 + lg * 4 + r;
        int s = m & 2047, b = m >> 11;
        float val = acc[mi][ni][r] + bval;
        size_t oidx = ((size_t)(b * 16 + h) * 2048 + s) * 64 + d;
        if (widx == 2) {
          vl[oidx] = f2bf(val);
        } else {
          float part = __shfl_xor(val, 1);
          float c = cosT[s * 32 + ia], sn = sinT[s * 32 + ia];
          float outv = (d & 1) ? (val * c + part * sn) : (val * c - part * sn);
          (widx == 0 ? ql : kl)[oidx] = f2bf(outv);
        }
      }
    }
  }
}

// ---------------- fused attention: swapped QK^T (S^T), no LDS, no barriers ----------------
__global__ __launch_bounds__(256, 2) void k_attn(
    const unsigned short* __restrict__ ql, const unsigned short* __restrict__ kl,
    const unsigned short* __restrict__ vt, const float* __restrict__ prev,
    float* __restrict__ scores, unsigned short* __restrict__ attn_out) {
  // bijective XCD swizzle: 4 bh per XCD-residue -> K/V (2MB) stays L2-resident
  int wg = blockIdx.x;                 // 0..511
  int c = wg >> 3, r = wg & 7;
  int bh = r * 4 + (c >> 4);
  int q0 = (c & 15) * 128;
  const int tid = threadIdx.x, lane = tid & 63, wave = tid >> 6;
  const int h = lane >> 5, qcol = lane & 31;
  const int q = q0 + wave * 32 + qcol;

  // Q fragments (B-operand: col=lane&31=q, k = h*8+e), hoisted
  const unsigned short* qrow = ql + ((size_t)bh * S_LEN + q) * DKH;
  s16x8 qf[4];
#pragma unroll
  for (int dk = 0; dk < 4; ++dk) qf[dk] = *(const s16x8*)(qrow + dk * 16 + h * 8);

  f32x16 o[2] = {};
  float m_run = -1e30f, l_run = 0.f;
  const float scale = 0.125f;
  const float* prevR = prev + (size_t)bh * S_LEN * S_LEN + (size_t)q * S_LEN;
  float* scoR = scores + (size_t)bh * S_LEN * S_LEN + (size_t)q * S_LEN;
  const unsigned short* kbase = kl + (size_t)bh * S_LEN * DKH;
  const unsigned short* vbase = vt + (size_t)bh * DKH * S_LEN + (size_t)qcol * S_LEN;

  for (int kv0 = 0; kv0 < S_LEN; kv0 += 128) {
    // ---- S^T = K · Q^T : per 32-kv tile, lane owns (q = its col, kv rows in regs)
    f32x16 sc[4];
#pragma unroll
    for (int t = 0; t < 4; ++t) {
      const unsigned short* krow = kbase + (size_t)(kv0 + t * 32 + qcol) * DKH + h * 8;
      f32x16 a = {};
#pragma unroll
      for (int dk = 0; dk < 4; ++dk) {
        s16x8 kf = *(const s16x8*)(krow + dk * 16);
        a = __builtin_amdgcn_mfma_f32_32x32x16_bf16(kf, qf[dk], a, 0, 0, 0);
      }
      sc[t] = a;
    }
    // ---- combine with prev (f32x4), stream scores out, lane-local max
    float tmax = -1e30f;
#pragma unroll
    for (int t = 0; t < 4; ++t) {
#pragma unroll
      for (int j = 0; j < 4; ++j) {
        int kvo = kv0 + t * 32 + 8 * j + 4 * h;
        f32x4 pv = __builtin_nontemporal_load((const f32x4*)(prevR + kvo));
        f32x4 sv;
        sv[0] = sc[t][4 * j + 0] * scale + pv[0];
        sv[1] = sc[t][4 * j + 1] * scale + pv[1];
        sv[2] = sc[t][4 * j + 2] * scale + pv[2];
        sv[3] = sc[t][4 * j + 3] * scale + pv[3];
        __builtin_nontemporal_store(sv, (f32x4*)(scoR + kvo));
        sc[t][4 * j + 0] = sv[0]; sc[t][4 * j + 1] = sv[1];
        sc[t][4 * j + 2] = sv[2]; sc[t][4 * j + 3] = sv[3];
        tmax = fmaxf(tmax, fmaxf(fmaxf(sv[0], sv[1]), fmaxf(sv[2], sv[3])));
      }
    }
    tmax = fmaxf(tmax, __shfl_xor(tmax, 32));  // merge half-pair (same q)
    float mn = fmaxf(m_run, tmax);
    float al = __expf(m_run - mn);
    m_run = mn;
    float lsum = 0.f;
#pragma unroll
    for (int t = 0; t < 4; ++t)
#pragma unroll
      for (int e = 0; e < 16; ++e) {
        float p = __expf(sc[t][e] - mn);
        sc[t][e] = p;
        lsum += p;
      }
    l_run = l_run * al + (lsum + __shfl_xor(lsum, 32));
#pragma unroll
    for (int dt = 0; dt < 2; ++dt)
#pragma unroll
      for (int e = 0; e < 16; ++e) o[dt][e] *= al;

    // ---- pack P^T B-fragments: pair-exchange kv quads via shfl_xor(32)
    s16x8 pb[8];
#pragma unroll
    for (int g = 0; g < 4; ++g) {
      unsigned int qu[4][2];
#pragma unroll
      for (int j = 0; j < 4; ++j) {
        qu[j][0] = pack2bf(sc[g][4 * j + 0], sc[g][4 * j + 1]);
        qu[j][1] = pack2bf(sc[g][4 * j + 2], sc[g][4 * j + 3]);
      }
      {
        unsigned int s0 = h ? qu[0][0] : qu[1][0];
        unsigned int s1 = h ? qu[0][1] : qu[1][1];
        unsigned int r0 = __shfl_xor(s0, 32);
        unsigned int r1 = __shfl_xor(s1, 32);
        union { s16x8 v; unsigned int u[4]; } fa;
        fa.u[0] = h ? r0 : qu[0][0];
        fa.u[1] = h ? r1 : qu[0][1];
        fa.u[2] = h ? qu[1][0] : r0;
        fa.u[3] = h ? qu[1][1] : r1;
        pb[2 * g] = fa.v;
      }
      {
        unsigned int s0 = h ? qu[2][0] : qu[3][0];
        unsigned int s1 = h ? qu[2][1] : qu[3][1];
        unsigned int r0 = __shfl_xor(s0, 32);
        unsigned int r1 = __shfl_xor(s1, 32);
        union { s16x8 v; unsigned int u[4]; } fb;
        fb.u[0] = h ? r0 : qu[2][0];
        fb.u[1] = h ? r1 : qu[2][1];
        fb.u[2] = h ? qu[3][0] : r0;
        fb.u[3] = h ? qu[3][1] : r1;
        pb[2 * g + 1] = fb.v;
      }
    }
    // ---- O^T += V^T · P^T
#pragma unroll
    for (int kt = 0; kt < 8; ++kt) {
      const unsigned short* vrow = vbase + kv0 + kt * 16 + h * 8;
#pragma unroll
      for (int dt = 0; dt < 2; ++dt) {
        s16x8 vf = *(const s16x8*)(vrow + (size_t)dt * 32 * S_LEN);
        o[dt] = __builtin_amdgcn_mfma_f32_32x32x16_bf16(vf, pb[kt], o[dt], 0, 0, 0);
      }
    }
  }

  float inv = 1.0f / l_run;
  int b = bh >> 4, hh = bh & 15;
  unsigned short* orow = attn_out + ((size_t)(b * S_LEN + q)) * 1024 + hh * 64;
#pragma unroll
  for (int dt = 0; dt < 2; ++dt)
#pragma unroll
    for (int jj = 0; jj < 4; ++jj) {
      s16x4 ov;
#pragma unroll
      for (int i = 0; i < 4; ++i) ov[i] = (short)f2bf(o[dt][4 * jj + i] * inv);
      *(s16x4*)(orow + dt * 32 + 8 * jj + 4 * h) = ov;
    }
}

// ---------------- output projection GEMM (m97-style) ----------------
__global__ __launch_bounds__(256) void k_outproj(
    const unsigned short* __restrict__ A, const unsigned short* __restrict__ WoT,
    const float* __restrict__ bo, float* __restrict__ out) {
  __shared__ unsigned short As[128 * 64];
  __shared__ unsigned short Bs[128 * 64];
  const int m0 = blockIdx.y * 128, n0 = blockIdx.x * 128;
  const int tid = threadIdx.x, lane = tid & 63, wave = tid >> 6;
  const int wm = (wave >> 1) * 64, wn = (wave & 1) * 64;
  const int lr = lane & 15, lg = lane >> 4;
  const int lrow = lane >> 3, lcol = (lane & 7) * 8;
  f32x4 acc[4][4] = {};
  for (int k0 = 0; k0 < 1024; k0 += 64) {
    __syncthreads();
#pragma unroll
    for (int i = 0; i < 4; ++i) {
      int chunk = wave * 4 + i;
      glds16(A + (size_t)(m0 + 8 * chunk + lrow) * 1024 + k0 + lcol, &As[chunk * 512]);
      glds16(WoT + (size_t)(n0 + 8 * chunk + lrow) * 1024 + k0 + lcol, &Bs[chunk * 512]);
    }
    __syncthreads();
#pragma unroll
    for (int ks = 0; ks < 2; ++ks) {
      s16x8 af[4], bf[4];
#pragma unroll
      for (int i = 0; i < 4; ++i) af[i] = *(const s16x8*)&As[(wm + i * 16 + lr) * 64 + ks * 32 + lg * 8];
#pragma unroll
      for (int i = 0; i < 4; ++i) bf[i] = *(const s16x8*)&Bs[(wn + i * 16 + lr) * 64 + ks * 32 + lg * 8];
#pragma unroll
      for (int mi = 0; mi < 4; ++mi)
#pragma unroll
        for (int ni = 0; ni < 4; ++ni)
          acc[mi][ni] = __builtin_amdgcn_mfma_f32_16x16x32_bf16(af[mi], bf[ni], acc[mi][ni], 0, 0, 0);
    }
  }
#pragma unroll
  for (int ni = 0; ni < 4; ++ni) {
    int n = n0 + wn + ni * 16 + lr;
    float bv = bo[n];
#pragma unroll
    for (int mi = 0; mi < 4; ++mi)
#pragma unroll
      for (int rr = 0; rr < 4; ++rr) {
        int m = m0 + wm + mi * 16 + lg * 4 + rr;
        out[(size_t)m * 1024 + n] = acc[mi][ni][rr] + bv;
      }
  }
}

extern "C" void kernel_launch(void* const* d_in, const int* in_sizes, int n_in,
                              void* d_out, int out_size, void* d_ws, size_t ws_size,
                              hipStream_t stream) {
  const float* Q = (const float*)d_in[0];
  const float* prev = (const float*)d_in[1];
  const float* Wq = (const float*)d_in[2];
  const float* bq = (const float*)d_in[3];
  const float* Wk = (const float*)d_in[4];
  const float* bk = (const float*)d_in[5];
  const float* Wv = (const float*)d_in[6];
  const float* bv = (const float*)d_in[7];
  const float* Wo = (const float*)d_in[8];
  const float* bo = (const float*)d_in[9];

  float* out = (float*)d_out;
  float* scores = out + (size_t)4194304;

  char* ws = (char*)d_ws;
  float* cosT = (float*)ws;
  float* sinT = cosT + 65536;
  unsigned short* WTqkv = (unsigned short*)(ws + 524288);  // [3072][1024]
  unsigned short* WoT = WTqkv + 3145728;                   // [1024][1024]
  unsigned short* ql = WoT + 1048576;                      // [32][2048][64]
  unsigned short* kl = ql + 4194304;
  unsigned short* vl = kl + 4194304;
  unsigned short* vt = vl + 4194304;                       // [32][64][2048]
  unsigned short* attn_out = vt + 4194304;                 // [4096][1024]
  unsigned short* Qbf = attn_out + 4194304;                // [4096][1024]

  k_rope_table<<<256, 256, 0, stream>>>(cosT, sinT);
  k_wtrans<<<dim3(32, 32), 256, 0, stream>>>(Wq, WTqkv);
  k_wtrans<<<dim3(32, 32), 256, 0, stream>>>(Wk, WTqkv + 1048576);
  k_wtrans<<<dim3(32, 32), 256, 0, stream>>>(Wv, WTqkv + 2097152);
  k_wtrans<<<dim3(32, 32), 256, 0, stream>>>(Wo, WoT);
  k_qconv<<<2048, 256, 0, stream>>>(Q, Qbf);
  k_qkv<<<dim3(24, 32), 256, 0, stream>>>(Qbf, WTqkv, bq, bk, bv, cosT, sinT, ql, kl, vl);
  k_vtrans<<<dim3(32, 32), 256, 0, stream>>>(vl, vt);
  k_attn<<<512, 256, 0, stream>>>(ql, kl, vt, prev, scores, attn_out);
  k_outproj<<<dim3(8, 32), 256, 0, stream>>>(attn_out, WoT, bo, out);
}

// Round 4
// 526.054 us; speedup vs baseline: 1.3619x; 1.3619x over previous
//
#include <hip/hip_runtime.h>
#include <hip/hip_bf16.h>
#include <math.h>
#include <cstdint>

#define S_LEN 2048
#define DKH 64

typedef __attribute__((ext_vector_type(8))) short s16x8;
typedef __attribute__((ext_vector_type(4))) float f32x4;

__device__ __forceinline__ unsigned short f2bf(float f) {
  unsigned int u = __float_as_uint(f);
  return (unsigned short)((u + 0x7fffu + ((u >> 16) & 1u)) >> 16);
}

// async global->LDS, 16B per lane, wave-uniform LDS base
__device__ __forceinline__ void glds16(const unsigned short* g, unsigned short* l) {
  __builtin_amdgcn_global_load_lds(
      (const __attribute__((address_space(1))) unsigned int*)(uintptr_t)g,
      (__attribute__((address_space(3))) unsigned int*)(uintptr_t)l, 16, 0, 0);
}

// ---------------- prep: rope table ----------------
__global__ void k_rope_table(float* __restrict__ cosT, float* __restrict__ sinT) {
  int idx = blockIdx.x * 256 + threadIdx.x;  // 2048*32
  if (idx >= S_LEN * 32) return;
  int s = idx >> 5, i = idx & 31;
  float theta = powf(10000.0f, -(float)i / 32.0f);
  float ang = (float)s * theta;
  float sv, cv;
  sincosf(ang, &sv, &cv);
  cosT[idx] = cv;
  sinT[idx] = sv;
}

// ---------------- prep: weight transpose f32[1024][1024] -> bf16 WT[n][k] ----------------
__global__ __launch_bounds__(256) void k_wtrans(const float* __restrict__ W,
                                                unsigned short* __restrict__ WT) {
  __shared__ float t[32][33];
  int n0 = blockIdx.x * 32, k0 = blockIdx.y * 32;
  int tx = threadIdx.x & 31, ty = threadIdx.x >> 5;
#pragma unroll
  for (int p = 0; p < 4; ++p)
    t[ty + p * 8][tx] = W[(size_t)(k0 + ty + p * 8) * 1024 + n0 + tx];
  __syncthreads();
#pragma unroll
  for (int p = 0; p < 4; ++p)
    WT[(size_t)(n0 + ty + p * 8) * 1024 + k0 + tx] = f2bf(t[tx][ty + p * 8]);
}

// ---------------- prep: Q f32 -> bf16 ----------------
__global__ __launch_bounds__(256) void k_qconv(const float* __restrict__ Q,
                                               unsigned short* __restrict__ Qbf) {
  int idx = (blockIdx.x * 256 + threadIdx.x) * 8;
  float4 a = *(const float4*)(Q + idx);
  float4 b = *(const float4*)(Q + idx + 4);
  s16x8 o;
  o[0] = (short)f2bf(a.x); o[1] = (short)f2bf(a.y); o[2] = (short)f2bf(a.z); o[3] = (short)f2bf(a.w);
  o[4] = (short)f2bf(b.x); o[5] = (short)f2bf(b.y); o[6] = (short)f2bf(b.z); o[7] = (short)f2bf(b.w);
  *(s16x8*)(Qbf + idx) = o;
}

// ---------------- prep: v transpose  vl[bh][s][d] -> vt[bh][d][s] (bf16) ----------------
__global__ __launch_bounds__(256) void k_vtrans(const unsigned short* __restrict__ vl,
                                                unsigned short* __restrict__ vt) {
  __shared__ unsigned short t[64][65];
  int bh = blockIdx.y;
  int s0 = blockIdx.x * 64;
  int tx = threadIdx.x & 3;
  int r = threadIdx.x >> 2;
  const unsigned short* src = vl + (size_t)bh * S_LEN * DKH + (size_t)s0 * DKH;
  s16x8 a = *(const s16x8*)(src + r * 64 + tx * 16);
  s16x8 b = *(const s16x8*)(src + r * 64 + tx * 16 + 8);
#pragma unroll
  for (int j = 0; j < 8; ++j) { t[r][tx * 16 + j] = (unsigned short)a[j]; t[r][tx * 16 + 8 + j] = (unsigned short)b[j]; }
  __syncthreads();
  unsigned short* dst = vt + (size_t)bh * DKH * S_LEN + (size_t)r * S_LEN + s0;
  s16x8 o0, o1;
#pragma unroll
  for (int j = 0; j < 8; ++j) { o0[j] = (short)t[tx * 16 + j][r]; o1[j] = (short)t[tx * 16 + 8 + j][r]; }
  *(s16x8*)(dst + tx * 16) = o0;
  *(s16x8*)(dst + tx * 16 + 8) = o1;
}

// ---------------- QKV projection GEMM (m97-style) + bias + RoPE ----------------
__global__ __launch_bounds__(256) void k_qkv(
    const unsigned short* __restrict__ Qbf, const unsigned short* __restrict__ WTqkv,
    const float* __restrict__ bq, const float* __restrict__ bk, const float* __restrict__ bv,
    const float* __restrict__ cosT, const float* __restrict__ sinT,
    unsigned short* __restrict__ ql, unsigned short* __restrict__ kl,
    unsigned short* __restrict__ vl) {
  __shared__ unsigned short As[128 * 64];
  __shared__ unsigned short Bs[128 * 64];
  const int m0 = blockIdx.y * 128, n0 = blockIdx.x * 128;
  const int tid = threadIdx.x, lane = tid & 63, wave = tid >> 6;
  const int wm = (wave >> 1) * 64, wn = (wave & 1) * 64;
  const int lr = lane & 15, lg = lane >> 4;
  const int widx = n0 >> 10;  // 0=q 1=k 2=v
  const float* bias = widx == 0 ? bq : (widx == 1 ? bk : bv);
  const int lrow = lane >> 3, lcol = (lane & 7) * 8;

  f32x4 acc[4][4] = {};
  for (int k0 = 0; k0 < 1024; k0 += 64) {
    __syncthreads();
#pragma unroll
    for (int i = 0; i < 4; ++i) {
      int chunk = wave * 4 + i;
      glds16(Qbf + (size_t)(m0 + 8 * chunk + lrow) * 1024 + k0 + lcol, &As[chunk * 512]);
      glds16(WTqkv + (size_t)(n0 + 8 * chunk + lrow) * 1024 + k0 + lcol, &Bs[chunk * 512]);
    }
    __syncthreads();
#pragma unroll
    for (int ks = 0; ks < 2; ++ks) {
      s16x8 af[4], bf[4];
#pragma unroll
      for (int i = 0; i < 4; ++i) af[i] = *(const s16x8*)&As[(wm + i * 16 + lr) * 64 + ks * 32 + lg * 8];
#pragma unroll
      for (int i = 0; i < 4; ++i) bf[i] = *(const s16x8*)&Bs[(wn + i * 16 + lr) * 64 + ks * 32 + lg * 8];
#pragma unroll
      for (int mi = 0; mi < 4; ++mi)
#pragma unroll
        for (int ni = 0; ni < 4; ++ni)
          acc[mi][ni] = __builtin_amdgcn_mfma_f32_16x16x32_bf16(af[mi], bf[ni], acc[mi][ni], 0, 0, 0);
    }
  }

#pragma unroll
  for (int ni = 0; ni < 4; ++ni) {
    int n = n0 + wn + ni * 16 + lr;
    int np = n & 1023;
    float bval = bias[np];
    int h = np >> 6, d = np & 63;
    int ia = d >> 1;
#pragma unroll
    for (int mi = 0; mi < 4; ++mi) {
#pragma unroll
      for (int r = 0; r < 4; ++r) {
        int m = m0 + wm + mi * 16 + lg * 4 + r;
        int s = m & 2047, b = m >> 11;
        float val = acc[mi][ni][r] + bval;
        size_t oidx = ((size_t)(b * 16 + h) * 2048 + s) * 64 + d;
        if (widx == 2) {
          vl[oidx] = f2bf(val);
        } else {
          float part = __shfl_xor(val, 1);
          float c = cosT[s * 32 + ia], sn = sinT[s * 32 + ia];
          float outv = (d & 1) ? (val * c + part * sn) : (val * c - part * sn);
          (widx == 0 ? ql : kl)[oidx] = f2bf(outv);
        }
      }
    }
  }
}

// ---------------- fused attention: 8-wave, LDS-staged K/V (glds16 + XOR swizzle) ----------------
__global__ __launch_bounds__(512, 4) void k_attn(
    const unsigned short* __restrict__ ql, const unsigned short* __restrict__ kl,
    const unsigned short* __restrict__ vt, const float* __restrict__ prev,
    float* __restrict__ scores, unsigned short* __restrict__ attn_out) {
  __shared__ unsigned short Ks[128 * 64];   // [kv 128][dk 64], rows 128B, XOR-swizzled
  __shared__ unsigned short Vs[64 * 128];   // [d 64][kv 128], rows 256B, XOR-swizzled
  __shared__ unsigned short Ps[8 * 16 * 128];  // per-wave [q 16][kv 128], rows 256B, swizzled

  // bijective XCD swizzle: each XCD owns 4 bh -> K/V (2MB) L2-resident
  int bid = blockIdx.x;            // 0..511
  int xcd = bid & 7, idx = bid >> 3;
  int bh = xcd * 4 + (idx >> 4);
  int qb = idx & 15;

  const int tid = threadIdx.x, lane = tid & 63, wave = tid >> 6;
  const int lr = lane & 15, lg = lane >> 4;
  const int qw = qb * 128 + wave * 16;

  // hoisted Q fragments (A-operand: row=lr, k=lg*8 within 32-slice)
  s16x8 qf[2];
#pragma unroll
  for (int ks = 0; ks < 2; ++ks)
    qf[ks] = *(const s16x8*)(ql + ((size_t)bh * S_LEN + qw + lr) * DKH + ks * 32 + lg * 8);

  f32x4 o[4] = {};
  float m_run[4], l_run[4];
#pragma unroll
  for (int r = 0; r < 4; ++r) { m_run[r] = -1e30f; l_run[r] = 0.f; }

  const float scale = 0.125f;
  const unsigned short* kbase = kl + (size_t)bh * S_LEN * DKH;
  const unsigned short* vbase = vt + (size_t)bh * DKH * S_LEN;
  const float* prevB = prev + (size_t)bh * S_LEN * S_LEN;
  float* scoB = scores + (size_t)bh * S_LEN * S_LEN;
  unsigned short* PsW = &Ps[wave * 2048];

  // staging lane decomposition
  const int kr = lane >> 3, kc = lane & 7;    // K: 8 rows x 8 chunks of 16B
  const int vr = lane >> 4, vc = lane & 15;   // V: 4 rows x 16 chunks of 16B

  for (int kv0 = 0; kv0 < S_LEN; kv0 += 128) {
    __syncthreads();  // prior tile's LDS reads done before restage
    // stage K (128 rows x 128B): wave w stages rows w*8.. and 64+w*8..
#pragma unroll
    for (int half = 0; half < 2; ++half) {
      int rbase = half * 64 + wave * 8;
      int row = rbase + kr;
      glds16(kbase + (size_t)(kv0 + row) * DKH + ((kc ^ (row & 7)) * 8), &Ks[rbase * 64]);
    }
    // stage V^T (64 rows x 256B): wave w stages d = w*8 .. w*8+8
#pragma unroll
    for (int half = 0; half < 2; ++half) {
      int dbase = wave * 8 + half * 4;
      int d = dbase + vr;
      glds16(vbase + (size_t)d * S_LEN + kv0 + ((vc ^ (d & 7)) * 8), &Vs[dbase * 128]);
    }
    __syncthreads();  // staging visible (drains vmcnt)

    // ---- QK^T: 8 n-tiles of 16 kv
    f32x4 sc[8];
#pragma unroll
    for (int n = 0; n < 8; ++n) {
      f32x4 a = {};
#pragma unroll
      for (int ks = 0; ks < 2; ++ks) {
        int row = n * 16 + lr;
        s16x8 kf = *(const s16x8*)((const char*)Ks +
                                   row * 128 + ((ks * 64 + lg * 16) ^ ((lr & 7) << 4)));
        a = __builtin_amdgcn_mfma_f32_16x16x32_bf16(qf[ks], kf, a, 0, 0, 0);
      }
      sc[n] = a;
    }

    // ---- + prev, stream scores, row max (coalesced: 16 lanes x 4B consecutive)
    float tmax[4] = {-1e30f, -1e30f, -1e30f, -1e30f};
#pragma unroll
    for (int n = 0; n < 8; ++n) {
      int col = kv0 + n * 16 + lr;
#pragma unroll
      for (int r = 0; r < 4; ++r) {
        int row = qw + lg * 4 + r;
        float pv = __builtin_nontemporal_load(prevB + (size_t)row * S_LEN + col);
        float v = sc[n][r] * scale + pv;
        __builtin_nontemporal_store(v, scoB + (size_t)row * S_LEN + col);
        sc[n][r] = v;
        tmax[r] = fmaxf(tmax[r], v);
      }
    }
#pragma unroll
    for (int mask = 1; mask < 16; mask <<= 1)
#pragma unroll
      for (int r = 0; r < 4; ++r) tmax[r] = fmaxf(tmax[r], __shfl_xor(tmax[r], mask));

    float al[4];
#pragma unroll
    for (int r = 0; r < 4; ++r) {
      float mn = fmaxf(m_run[r], tmax[r]);
      al[r] = __expf(m_run[r] - mn);
      m_run[r] = mn;
      l_run[r] *= al[r];
    }
#pragma unroll
    for (int df = 0; df < 4; ++df)
#pragma unroll
      for (int r = 0; r < 4; ++r) o[df][r] *= al[r];

    // ---- P = exp(S - m), write to per-wave swizzled Ps
#pragma unroll
    for (int n = 0; n < 8; ++n) {
#pragma unroll
      for (int r = 0; r < 4; ++r) {
        float p = __expf(sc[n][r] - m_run[r]);
        l_run[r] += p;
        int prow = lg * 4 + r;
        *(unsigned short*)((char*)PsW + prow * 256 +
                           ((n * 32 + lr * 2) ^ ((prow & 7) << 4))) = f2bf(p);
      }
    }
    // per-wave LDS: same-wave DS ops are in-order; no barrier needed

    // ---- PV: O += P * V^T
#pragma unroll
    for (int df = 0; df < 4; ++df) {
#pragma unroll
      for (int ks = 0; ks < 4; ++ks) {
        s16x8 pa = *(const s16x8*)((const char*)PsW +
                                   lr * 256 + ((ks * 64 + lg * 16) ^ ((lr & 7) << 4)));
        int vrow = df * 16 + lr;
        s16x8 vb = *(const s16x8*)((const char*)Vs +
                                   vrow * 256 + ((ks * 64 + lg * 16) ^ ((lr & 7) << 4)));
        o[df] = __builtin_amdgcn_mfma_f32_16x16x32_bf16(pa, vb, o[df], 0, 0, 0);
      }
    }
  }

#pragma unroll
  for (int mask = 1; mask < 16; mask <<= 1)
#pragma unroll
    for (int r = 0; r < 4; ++r) l_run[r] += __shfl_xor(l_run[r], mask);
  float inv[4];
#pragma unroll
  for (int r = 0; r < 4; ++r) inv[r] = 1.0f / l_run[r];

  int b = bh >> 4, h = bh & 15;
#pragma unroll
  for (int df = 0; df < 4; ++df) {
    int d = df * 16 + lr;
#pragma unroll
    for (int r = 0; r < 4; ++r) {
      int row = qw + lg * 4 + r;
      attn_out[((size_t)(b * S_LEN + row)) * 1024 + h * 64 + d] = f2bf(o[df][r] * inv[r]);
    }
  }
}

// ---------------- output projection GEMM (m97-style) ----------------
__global__ __launch_bounds__(256) void k_outproj(
    const unsigned short* __restrict__ A, const unsigned short* __restrict__ WoT,
    const float* __restrict__ bo, float* __restrict__ out) {
  __shared__ unsigned short As[128 * 64];
  __shared__ unsigned short Bs[128 * 64];
  const int m0 = blockIdx.y * 128, n0 = blockIdx.x * 128;
  const int tid = threadIdx.x, lane = tid & 63, wave = tid >> 6;
  const int wm = (wave >> 1) * 64, wn = (wave & 1) * 64;
  const int lr = lane & 15, lg = lane >> 4;
  const int lrow = lane >> 3, lcol = (lane & 7) * 8;
  f32x4 acc[4][4] = {};
  for (int k0 = 0; k0 < 1024; k0 += 64) {
    __syncthreads();
#pragma unroll
    for (int i = 0; i < 4; ++i) {
      int chunk = wave * 4 + i;
      glds16(A + (size_t)(m0 + 8 * chunk + lrow) * 1024 + k0 + lcol, &As[chunk * 512]);
      glds16(WoT + (size_t)(n0 + 8 * chunk + lrow) * 1024 + k0 + lcol, &Bs[chunk * 512]);
    }
    __syncthreads();
#pragma unroll
    for (int ks = 0; ks < 2; ++ks) {
      s16x8 af[4], bf[4];
#pragma unroll
      for (int i = 0; i < 4; ++i) af[i] = *(const s16x8*)&As[(wm + i * 16 + lr) * 64 + ks * 32 + lg * 8];
#pragma unroll
      for (int i = 0; i < 4; ++i) bf[i] = *(const s16x8*)&Bs[(wn + i * 16 + lr) * 64 + ks * 32 + lg * 8];
#pragma unroll
      for (int mi = 0; mi < 4; ++mi)
#pragma unroll
        for (int ni = 0; ni < 4; ++ni)
          acc[mi][ni] = __builtin_amdgcn_mfma_f32_16x16x32_bf16(af[mi], bf[ni], acc[mi][ni], 0, 0, 0);
    }
  }
#pragma unroll
  for (int ni = 0; ni < 4; ++ni) {
    int n = n0 + wn + ni * 16 + lr;
    float bv = bo[n];
#pragma unroll
    for (int mi = 0; mi < 4; ++mi)
#pragma unroll
      for (int rr = 0; rr < 4; ++rr) {
        int m = m0 + wm + mi * 16 + lg * 4 + rr;
        out[(size_t)m * 1024 + n] = acc[mi][ni][rr] + bv;
      }
  }
}

extern "C" void kernel_launch(void* const* d_in, const int* in_sizes, int n_in,
                              void* d_out, int out_size, void* d_ws, size_t ws_size,
                              hipStream_t stream) {
  const float* Q = (const float*)d_in[0];
  const float* prev = (const float*)d_in[1];
  const float* Wq = (const float*)d_in[2];
  const float* bq = (const float*)d_in[3];
  const float* Wk = (const float*)d_in[4];
  const float* bk = (const float*)d_in[5];
  const float* Wv = (const float*)d_in[6];
  const float* bv = (const float*)d_in[7];
  const float* Wo = (const float*)d_in[8];
  const float* bo = (const float*)d_in[9];

  float* out = (float*)d_out;
  float* scores = out + (size_t)4194304;

  char* ws = (char*)d_ws;
  float* cosT = (float*)ws;
  float* sinT = cosT + 65536;
  unsigned short* WTqkv = (unsigned short*)(ws + 524288);  // [3072][1024]
  unsigned short* WoT = WTqkv + 3145728;                   // [1024][1024]
  unsigned short* ql = WoT + 1048576;                      // [32][2048][64]
  unsigned short* kl = ql + 4194304;
  unsigned short* vl = kl + 4194304;
  unsigned short* vt = vl + 4194304;                       // [32][64][2048]
  unsigned short* attn_out = vt + 4194304;                 // [4096][1024]
  unsigned short* Qbf = attn_out + 4194304;                // [4096][1024]

  k_rope_table<<<256, 256, 0, stream>>>(cosT, sinT);
  k_wtrans<<<dim3(32, 32), 256, 0, stream>>>(Wq, WTqkv);
  k_wtrans<<<dim3(32, 32), 256, 0, stream>>>(Wk, WTqkv + 1048576);
  k_wtrans<<<dim3(32, 32), 256, 0, stream>>>(Wv, WTqkv + 2097152);
  k_wtrans<<<dim3(32, 32), 256, 0, stream>>>(Wo, WoT);
  k_qconv<<<2048, 256, 0, stream>>>(Q, Qbf);
  k_qkv<<<dim3(24, 32), 256, 0, stream>>>(Qbf, WTqkv, bq, bk, bv, cosT, sinT, ql, kl, vl);
  k_vtrans<<<dim3(32, 32), 256, 0, stream>>>(vl, vt);
  k_attn<<<512, 512, 0, stream>>>(ql, kl, vt, prev, scores, attn_out);
  k_outproj<<<dim3(8, 32), 256, 0, stream>>>(attn_out, WoT, bo, out);
}